// Round 6
// baseline (597.434 us; speedup 1.0000x reference)
//
#include <hip/hip_runtime.h>
#include <hip/hip_bf16.h>

// Problem constants
#define BB   2
#define SS   2048
#define DD   2560
#define HH   8
#define HKVV 4
#define HDD  256
#define MM   (BB*SS)      // 4096 rows
#define NQ   (HH*HDD)     // 2048
#define NKV  (HKVV*HDD)   // 1024
#define SCALING 0.0625f   // 256^-0.5
#define SOFTCAP 4096.0f
#define CAPC    (1.0f/(3.0f*SOFTCAP*SOFTCAP))  // cubic softcap coefficient
#define M0      20.0f     // fixed softmax max: |scores| <= 16.2 by Cauchy-Schwarz

typedef __attribute__((ext_vector_type(8))) short short8;       // 8 bf16 (4 VGPR)
typedef __attribute__((ext_vector_type(8))) unsigned short ushort8;
typedef __attribute__((ext_vector_type(4))) unsigned short us4;
typedef __attribute__((ext_vector_type(4))) float f32x4;        // MFMA C/D

__device__ __forceinline__ float bf2f(unsigned short u) {
    union { unsigned int i; float f; } v; v.i = ((unsigned int)u) << 16; return v.f;
}
__device__ __forceinline__ unsigned short f2bf(float f) {
    union { float f; unsigned int i; } v; v.f = f;
    return (unsigned short)((v.i + 0x7fffu + ((v.i >> 16) & 1u)) >> 16);
}
__device__ __forceinline__ f32x4 mfma16(short8 a, short8 b, f32x4 c) {
    return __builtin_amdgcn_mfma_f32_16x16x32_bf16(a, b, c, 0, 0, 0);
}

// async global->LDS, 16B per lane (gfx950). LDS dest must be tid-linear.
__device__ __forceinline__ void async_cp16(const void* g, void* l) {
    __builtin_amdgcn_global_load_lds(
        (__attribute__((address_space(1))) void*)(g),
        (__attribute__((address_space(3))) void*)(l), 16, 0, 0);
}

// dtype-polymorphic helpers
__device__ __forceinline__ ushort8 ld8(const unsigned short* p) { return *(const ushort8*)p; }
__device__ __forceinline__ ushort8 ld8(const float* p) {
    ushort8 r;
#pragma unroll
    for (int i = 0; i < 8; i++) r[i] = f2bf(p[i]);
    return r;
}
__device__ __forceinline__ void stc(float* p, float v)          { *p = v; }
__device__ __forceinline__ void stc(unsigned short* p, float v) { *p = f2bf(v); }
// staging: bf16 source -> async DMA; fp32 source -> in-reg convert + LDS write
__device__ __forceinline__ void stage8(const unsigned short* src, unsigned short* lds) {
    async_cp16(src, lds);
}
__device__ __forceinline__ void stage8(const float* src, unsigned short* lds) {
    *(ushort8*)lds = ld8(src);
}

// ---------------------------------------------------------------------------
// fp32 -> bf16 bulk convert (RNE), float4-vectorized grid-stride
// ---------------------------------------------------------------------------
__global__ __launch_bounds__(256) void cvt_bf16(const float* __restrict__ in,
                                                unsigned short* __restrict__ out, int n4)
{
    int i = blockIdx.x * 256 + threadIdx.x;
    const int stride = gridDim.x * 256;
    for (; i < n4; i += stride) {
        float4 v = ((const float4*)in)[i];
        us4 o;
        o[0] = f2bf(v.x); o[1] = f2bf(v.y); o[2] = f2bf(v.z); o[3] = f2bf(v.w);
        ((us4*)out)[i] = o;
    }
}

// ---------------------------------------------------------------------------
// Unified GEMM: C(M,N) = A(M,K) @ B(N,K)^T. bf16 operands staged via
// global_load_lds(16B); fp32 operands converted in-reg. TM x 128 tile
// (TM=128 or 64), 4 waves in 2x2, BK=32. VT_OUT: epilogue writes V^T
// (b,kvh,d,s) instead of row-major C.
// ---------------------------------------------------------------------------
template<typename TA, typename TB, typename TC, int TM, bool VT_OUT>
__global__ __launch_bounds__(256) void gemm_k(const TA* __restrict__ A,
                                              const TB* __restrict__ Bm,
                                              TC* __restrict__ C,
                                              int M, int N, int K)
{
    constexpr int MI = TM / 32;          // per-wave 16-row tiles (wave = TM/2 rows)
    __shared__ __align__(16) unsigned short As[TM][32];
    __shared__ __align__(16) unsigned short Bs[128][32];

    const int tid  = threadIdx.x;
    const int bm   = blockIdx.x, bn = blockIdx.y;
    const int wave = tid >> 6, lane = tid & 63;
    const int quad = lane >> 4, lm = lane & 15;
    const int wm = (wave >> 1) * (TM / 2), wn = (wave & 1) * 64;

    f32x4 acc[MI][4];
#pragma unroll
    for (int i = 0; i < MI; i++)
#pragma unroll
        for (int j = 0; j < 4; j++) acc[i][j] = (f32x4)0.0f;

    unsigned short* AsF = &As[0][0];
    unsigned short* BsF = &Bs[0][0];
    const int grow = tid >> 2;           // 0..63
    const int gcol = (tid & 3) * 8;      // 0,8,16,24
    const TA* Ab = A  + (size_t)(bm * TM) * K;
    const TB* Bb = Bm + (size_t)(bn * 128) * K;

    for (int k0 = 0; k0 < K; k0 += 32) {
#pragma unroll
        for (int rr = 0; rr < TM / 64; rr++)
            stage8(&Ab[(size_t)(grow + rr * 64) * K + k0 + gcol], AsF + rr * 2048 + tid * 8);
        stage8(&Bb[(size_t)(grow     ) * K + k0 + gcol], BsF + tid * 8);
        stage8(&Bb[(size_t)(grow + 64) * K + k0 + gcol], BsF + 2048 + tid * 8);
        __syncthreads();   // drains vmcnt/lgkmcnt -> LDS valid

        short8 af[MI], bf[4];
#pragma unroll
        for (int t = 0; t < MI; t++) af[t] = *(const short8*)&As[wm + t * 16 + lm][quad * 8];
#pragma unroll
        for (int t = 0; t < 4; t++) bf[t] = *(const short8*)&Bs[wn + t * 16 + lm][quad * 8];
#pragma unroll
        for (int i = 0; i < MI; i++)
#pragma unroll
            for (int j = 0; j < 4; j++)
                acc[i][j] = mfma16(af[i], bf[j], acc[i][j]);
        __syncthreads();
    }

    // C/D layout: row = quad*4 + r, col = lm  [verified m89/m91]
#pragma unroll
    for (int i = 0; i < MI; i++)
#pragma unroll
        for (int j = 0; j < 4; j++) {
            if constexpr (VT_OUT) {
                int row0 = bm * TM + wm + i * 16 + quad * 4;    // b*SS + s0
                int col  = bn * 128 + wn + j * 16 + lm;         // kvh*HDD + d
                int b    = row0 >> 11, s0 = row0 & (SS - 1);
                int kvh  = col >> 8,   d  = col & (HDD - 1);
                us4 pk;
#pragma unroll
                for (int r = 0; r < 4; r++) pk[r] = f2bf(acc[i][j][r]);
                *(us4*)&C[(((size_t)b * HKVV + kvh) * HDD + d) * SS + s0] = pk;
            } else {
#pragma unroll
                for (int r = 0; r < 4; r++) {
                    int row = bm * TM + wm + i * 16 + quad * 4 + r;
                    int col = bn * 128 + wn + j * 16 + lm;
                    stc(&C[(size_t)row * N + col], acc[i][j][r]);
                }
            }
        }
}

// ---------------------------------------------------------------------------
// Fused RMSNorm + RoPE in place on bf16 X (b, s, h, d), one block per (bs,h).
// ---------------------------------------------------------------------------
__global__ __launch_bounds__(256) void norm_rope(unsigned short* __restrict__ X,
                                                 const float* __restrict__ nw,
                                                 const float* __restrict__ cosb,
                                                 const float* __restrict__ sinb,
                                                 int nheads)
{
    const int bs = blockIdx.x;
    const int h  = blockIdx.y;
    const int t  = threadIdx.x;

    __shared__ float xs[256];
    __shared__ float red[4];

    const size_t base = ((size_t)bs * nheads + h) * HDD;
    float v = bf2f(X[base + t]);
    xs[t] = v;

    float p = v * v;
#pragma unroll
    for (int off = 32; off >= 1; off >>= 1) p += __shfl_xor(p, off);
    if ((t & 63) == 0) red[t >> 6] = p;
    __syncthreads();
    float sum = red[0] + red[1] + red[2] + red[3];
    float rs  = rsqrtf(sum * (1.0f / HDD) + 1e-6f);

    const int pt = (t + 128) & 255;
    float w1 = 1.0f + nw[t];
    float w2 = 1.0f + nw[pt];
    float normed  = v * rs * w1;
    float partner = xs[pt] * rs * w2;
    float rot = (t < 128) ? -partner : partner;   // rotate_half: [-x2, x1]
    float c = cosb[(size_t)bs * HDD + t];
    float s = sinb[(size_t)bs * HDD + t];
    X[base + t] = f2bf(normed * c + rot * s);
}

// ---------------------------------------------------------------------------
// Block-cooperative flash attention: causal, GQA, cubic softcap, fixed-max
// softmax. Flat grid of 512; id&7 selects (b,kvh) so (with the %8 XCD
// round-robin heuristic) each XCD's L2 keeps its 2 MB K/V slice resident.
// Double-buffered K/V LDS tiles (32 keys): one barrier per step; DMA for
// step t+1 issued right after the barrier, covered by step-t compute.
// ---------------------------------------------------------------------------
__global__ __launch_bounds__(256) void attn_kernel(const unsigned short* __restrict__ Q,
                                                   const unsigned short* __restrict__ K,
                                                   const unsigned short* __restrict__ VT,
                                                   unsigned short* __restrict__ O)
{
    const int tid = threadIdx.x, w = tid >> 6, lane = tid & 63;
    const int quad = lane >> 4, lm = lane & 15;

    const int id  = blockIdx.x;                 // 0..511
    const int xcd = id & 7;
    const int b   = xcd >> 2, kvh = xcd & 3;
    const int j   = id >> 3;                    // 0..63
    const int hp  = j & 1, jj = j >> 1;         // 0..31
    const int qb  = (jj & 1) ? (31 - (jj >> 1)) : (jj >> 1);  // heavy/light mix
    const int h   = kvh * 2 + hp;
    const int q0  = qb * 64;
    const int T   = 2 * (qb + 1);               // 32-key steps

    __shared__ __align__(16) unsigned short Ks[2][32 * 256]; // 2 x 16 KB
    __shared__ __align__(16) unsigned short Vt[2][256 * 32]; // 2 x 16 KB
    __shared__ __align__(16) unsigned short Ps[4 * 512];     // per-wave P round-trip

    // Q A-fragments: lane holds Q[m=lm][k=quad*8+jj] per 32-wide chunk c
    const unsigned short* Qb = Q + (((size_t)b * SS + q0 + w * 16 + lm) * HH + h) * HDD;
    short8 qf[8];
#pragma unroll
    for (int c = 0; c < 8; c++) qf[c] = *(const short8*)&Qb[c * 32 + quad * 8];

    const unsigned short* Kb = K  + (size_t)b * SS * NKV + (size_t)kvh * HDD;    // row s, stride NKV
    const unsigned short* Vb = VT + ((size_t)b * HKVV + kvh) * HDD * (size_t)SS; // row d, stride SS

    f32x4 o_acc[16];
#pragma unroll
    for (int i = 0; i < 16; i++) o_acc[i] = (f32x4)0.0f;
    float l_r[4] = {0.f, 0.f, 0.f, 0.f};

    const int mylo = q0 + w * 16;
    const int row  = mylo + quad * 4;

    // stage one 32-key K/V tile into buffer bi (tid-linear DMA, 8 cp/thread)
    auto stage = [&](int bi, int k0) {
#pragma unroll
        for (int p = 0; p < 4; p++) {
            const int slot = p * 256 + tid;      // 0..1023
            const int kr = slot >> 5, kc = slot & 31;
            async_cp16(&Kb[(size_t)(k0 + kr) * NKV + kc * 8], &Ks[bi][slot * 8]);
            const int vd = slot >> 2, vc = slot & 3;
            async_cp16(&Vb[(size_t)vd * SS + k0 + vc * 8], &Vt[bi][slot * 8]);
        }
    };

    stage(0, 0);
    for (int t = 0; t < T; t++) {
        __syncthreads();                         // drains DMA for buf[t&1]
        if (t + 1 < T) stage((t + 1) & 1, (t + 1) * 32);   // in flight across compute
        const int k0 = t * 32, cur = t & 1;

        if (k0 <= mylo + 15) {                   // wave-uniform causal skip
            // ---- S = Q K^T (16 x 32) ----
            f32x4 sa0 = (f32x4)0.0f, sa1 = (f32x4)0.0f;
#pragma unroll
            for (int c = 0; c < 8; c++) {
                short8 kf0 = *(const short8*)&Ks[cur][lm * 256 + c * 32 + quad * 8];
                short8 kf1 = *(const short8*)&Ks[cur][(16 + lm) * 256 + c * 32 + quad * 8];
                sa0 = mfma16(qf[c], kf0, sa0);
                sa1 = mfma16(qf[c], kf1, sa1);
            }

            // ---- cubic softcap + fixed-max exp (no cross-lane) ----
            const bool msk = (k0 + 31 > mylo);
            float pe[2][4];
#pragma unroll
            for (int t2 = 0; t2 < 2; t2++) {
                const int key = k0 + t2 * 16 + lm;
#pragma unroll
                for (int r = 0; r < 4; r++) {
                    float s = (t2 ? sa1[r] : sa0[r]) * SCALING;
                    s = s - s * s * s * CAPC;            // ~= SOFTCAP*tanh(s/SOFTCAP)
                    float e = __expf(s - M0);
                    if (msk && key > row + r) e = 0.0f;
                    pe[t2][r] = e;
                    l_r[r] += e;
                }
            }

            // ---- P: C layout -> A layout via swizzled per-wave LDS ----
#pragma unroll
            for (int t2 = 0; t2 < 2; t2++)
#pragma unroll
                for (int r = 0; r < 4; r++) {
                    const int g = (t2 * 2 + (lm >> 3)) ^ r ^ quad;
                    Ps[w * 512 + (quad * 4 + r) * 32 + g * 8 + (lm & 7)] = f2bf(pe[t2][r]);
                }
            asm volatile("s_waitcnt lgkmcnt(0)" ::: "memory");
            const int gr = quad ^ (lm & 3) ^ (lm >> 2);
            short8 pf = *(const short8*)&Ps[w * 512 + lm * 32 + gr * 8];

            // ---- O += P V ----
#pragma unroll
            for (int nt = 0; nt < 16; nt++) {
                short8 vf = *(const short8*)&Vt[cur][(nt * 16 + lm) * 32 + quad * 8];
                o_acc[nt] = mfma16(pf, vf, o_acc[nt]);
            }
        }
    }

    // ---- epilogue: reduce l over 16-lane col group, normalize, store ----
#pragma unroll
    for (int off = 1; off < 16; off <<= 1)
#pragma unroll
        for (int r = 0; r < 4; r++) l_r[r] += __shfl_xor(l_r[r], off);
#pragma unroll
    for (int r = 0; r < 4; r++) {
        float inv = 1.0f / l_r[r];
        unsigned short* Ob = O + ((size_t)b * SS + row + r) * NQ + h * HDD;
#pragma unroll
        for (int nt = 0; nt < 16; nt++)
            Ob[nt * 16 + lm] = f2bf(o_acc[nt][r] * inv);
    }
}

// ---------------------------------------------------------------------------
// Workspace (shorts), total 50,331,648 B == round-3's proven-safe size:
//   [ATT 8.39M][Q 8.39M][K 4.19M][VT 4.19M]
//   wq+wk bf16 alias ATT (dead until attn); wv bf16 aliases K (V-GEMM runs
//   before K-GEMM); wo bf16 aliases Q after attn. Optional xb beyond base.
// ---------------------------------------------------------------------------
extern "C" void kernel_launch(void* const* d_in, const int* in_sizes, int n_in,
                              void* d_out, int out_size, void* d_ws, size_t ws_size,
                              hipStream_t stream)
{
    const float* x    = (const float*)d_in[0];
    const float* cosb = (const float*)d_in[1];
    const float* sinb = (const float*)d_in[2];
    // d_in[3] = mask (pure causal + NEG, reimplemented in-kernel)
    const float* q_w  = (const float*)d_in[4];
    const float* k_w  = (const float*)d_in[5];
    const float* v_w  = (const float*)d_in[6];
    const float* o_w  = (const float*)d_in[7];
    const float* qn_w = (const float*)d_in[8];
    const float* kn_w = (const float*)d_in[9];
    float* out = (float*)d_out;

    const size_t sz_att = (size_t)MM * NQ;    // 8388608
    const size_t sz_q   = (size_t)MM * NQ;    // 8388608
    const size_t sz_k   = (size_t)MM * NKV;   // 4194304
    const size_t sz_wq  = (size_t)NQ * DD;    // 5242880
    const size_t sz_wk  = (size_t)NKV * DD;   // 2621440
    const size_t sz_xb  = (size_t)MM * DD;    // 10485760

    unsigned short* base = (unsigned short*)d_ws;
    unsigned short* ATT  = base;                       // also wq|wk until attn
    unsigned short* Qw   = base + sz_att;              // also wo after attn
    unsigned short* Kw   = Qw + sz_q;                  // also wv until K-GEMM
    unsigned short* VTw  = Kw + sz_k;

    unsigned short* wqb = ATT;
    unsigned short* wkb = ATT + sz_wq;
    unsigned short* wvb = Kw;
    unsigned short* wob = Qw;
    unsigned short* xb  = VTw + sz_k;

    const bool have_xb = ws_size >= (size_t)(VTw + sz_k + sz_xb - base) * 2;

    // weight conversions (regions currently dead)
    cvt_bf16<<<2048, 256, 0, stream>>>(q_w, wqb, (int)(sz_wq / 4));
    cvt_bf16<<<1024, 256, 0, stream>>>(k_w, wkb, (int)(sz_wk / 4));
    cvt_bf16<<<1024, 256, 0, stream>>>(v_w, wvb, (int)(sz_wk / 4));

    if (have_xb) {
        cvt_bf16<<<2048, 256, 0, stream>>>(x, xb, (int)(sz_xb / 4));
        // V first (reads wvb in K region), then Q, then K (overwrites wvb)
        gemm_k<unsigned short, unsigned short, unsigned short,  64, true>
            <<<dim3(MM/64,  NKV/128), 256, 0, stream>>>(xb, wvb, VTw, MM, NKV, DD);
        gemm_k<unsigned short, unsigned short, unsigned short, 128, false>
            <<<dim3(MM/128, NQ /128), 256, 0, stream>>>(xb, wqb, Qw,  MM, NQ,  DD);
        gemm_k<unsigned short, unsigned short, unsigned short,  64, false>
            <<<dim3(MM/64,  NKV/128), 256, 0, stream>>>(xb, wkb, Kw,  MM, NKV, DD);
    } else {
        gemm_k<float, unsigned short, unsigned short,  64, true>
            <<<dim3(MM/64,  NKV/128), 256, 0, stream>>>(x, wvb, VTw, MM, NKV, DD);
        gemm_k<float, unsigned short, unsigned short, 128, false>
            <<<dim3(MM/128, NQ /128), 256, 0, stream>>>(x, wqb, Qw,  MM, NQ,  DD);
        gemm_k<float, unsigned short, unsigned short,  64, false>
            <<<dim3(MM/64,  NKV/128), 256, 0, stream>>>(x, wkb, Kw,  MM, NKV, DD);
    }

    norm_rope<<<dim3(MM, HH),   256, 0, stream>>>(Qw, qn_w, cosb, sinb, HH);
    norm_rope<<<dim3(MM, HKVV), 256, 0, stream>>>(Kw, kn_w, cosb, sinb, HKVV);

    // attention writes ATT (wq/wk dead)
    attn_kernel<<<512, 256, 0, stream>>>(Qw, Kw, VTw, ATT);

    // O-proj weights into dead Q region; fully-async bf16 GEMM
    cvt_bf16<<<2048, 256, 0, stream>>>(o_w, wob, (int)(sz_wq / 4));
    gemm_k<unsigned short, unsigned short, float, 128, false>
        <<<dim3(MM/128, DD/128), 256, 0, stream>>>(ATT, wob, out, MM, DD, NQ);
}